// Round 4
// baseline (191.682 us; speedup 1.0000x reference)
//
#include <hip/hip_runtime.h>
#include <stdint.h>

#define B_  2
#define S_  768
#define D_  768
#define H_  8
#define DH_ 96

typedef unsigned short ushort_t;
typedef __bf16 bf16x8 __attribute__((ext_vector_type(8)));
typedef float  f32x4  __attribute__((ext_vector_type(4)));
typedef _Float16 f16x4 __attribute__((ext_vector_type(4)));

__device__ inline ushort_t f2bf(float f) {
    union { float f; unsigned int u; } v; v.f = f;
    unsigned int u = v.u;
    unsigned int r = u + 0x7fffu + ((u >> 16) & 1u);
    return (ushort_t)(r >> 16);
}
__device__ inline float bf2f(ushort_t u) {
    union { unsigned int i; float f; } c; c.i = ((unsigned int)u) << 16;
    return c.f;
}
__device__ inline ushort_t f2h(float f) {
    union { _Float16 h; ushort_t u; } c; c.h = (_Float16)f; return c.u;
}

// async global->LDS, 16B per lane; LDS dest is wave-uniform base + lane*16,
// global source is per-lane.
__device__ inline void glds16(const void* gp, void* lp) {
    auto g = reinterpret_cast<const __attribute__((address_space(1))) uint32_t*>(
        reinterpret_cast<uintptr_t>(gp));
    auto l = reinterpret_cast<__attribute__((address_space(3))) uint32_t*>(
        reinterpret_cast<uintptr_t>(lp));
    __builtin_amdgcn_global_load_lds(g, l, 16, 0, 0);
}

// ---------------------------------------------------------------- convert
// X,Wq..Wo -> bf16; dist/ang -> fp16 (into xbuf region, dead until k_out).
__global__ __launch_bounds__(256) void k_convert(
        const float* __restrict__ X, const float* __restrict__ Wq,
        const float* __restrict__ Wk, const float* __restrict__ Wv,
        const float* __restrict__ Wo, const float* __restrict__ distm,
        const float* __restrict__ angm,
        ushort_t* __restrict__ Xb, ushort_t* __restrict__ Wb,
        ushort_t* __restrict__ Dh, ushort_t* __restrict__ Ah) {
    const int NX4 = (B_ * S_ * D_) / 4;   // 294912
    const int NW4 = (D_ * D_) / 4;        // 147456
    const int NWall = 4 * NW4;            // 589824
    const int ND4 = (B_ * S_ * S_) / 4;   // 294912
    int i = blockIdx.x * blockDim.x + threadIdx.x;
    float4 v;
    ushort_t* dst;
    bool h16 = false;
    if (i < NX4) {
        v = ((const float4*)X)[i];
        dst = Xb + i * 4;
    } else if (i < NX4 + NWall) {
        int wi = i - NX4;
        int sel = wi / NW4;
        int off = wi - sel * NW4;
        const float* src = (sel == 0) ? Wq : (sel == 1) ? Wk : (sel == 2) ? Wv : Wo;
        v = ((const float4*)src)[off];
        dst = Wb + wi * 4;
    } else if (i < NX4 + NWall + ND4) {
        int off = i - NX4 - NWall;
        v = ((const float4*)distm)[off];
        dst = Dh + off * 4; h16 = true;
    } else {
        int off = i - NX4 - NWall - ND4;
        v = ((const float4*)angm)[off];
        dst = Ah + off * 4; h16 = true;
    }
    ushort4 o;
    if (h16) { o.x = f2h(v.x); o.y = f2h(v.y); o.z = f2h(v.z); o.w = f2h(v.w); }
    else     { o.x = f2bf(v.x); o.y = f2bf(v.y); o.z = f2bf(v.z); o.w = f2bf(v.w); }
    *(ushort4*)dst = o;
}

// ---------------------------------------------------------------- 64x64 GEMM, double-buffered glds
__device__ inline void gemm64_dbuf(
        const ushort_t* __restrict__ A, int lda,
        const ushort_t* __restrict__ Bt, int ldb,
        int K, int m0, int n0,
        ushort_t* As, ushort_t* Bs, f32x4 acc[2][2]) {
    const int tid  = threadIdx.x;
    const int lane = tid & 63, wave = tid >> 6;
    const int wm = (wave >> 1) * 32, wn = (wave & 1) * 32;
    const int fr = lane & 15, fk = (lane >> 4) * 8;
    const ushort_t* Ap = A  + (size_t)(m0 + wave * 16 + (lane >> 2)) * lda + (lane & 3) * 8;
    const ushort_t* Bp = Bt + (size_t)(n0 + wave * 16 + (lane >> 2)) * ldb + (lane & 3) * 8;
    glds16(Ap, As + wave * 512);
    glds16(Bp, Bs + wave * 512);
    for (int kt = 0; kt < K; kt += 32) {
        const int cur = (kt >> 5) & 1;
        __syncthreads();
        if (kt + 32 < K) {
            glds16(Ap + kt + 32, As + (cur ^ 1) * 2048 + wave * 512);
            glds16(Bp + kt + 32, Bs + (cur ^ 1) * 2048 + wave * 512);
        }
        const ushort_t* Ab = As + cur * 2048;
        const ushort_t* Bb = Bs + cur * 2048;
        bf16x8 a0 = *(const bf16x8*)&Ab[(wm      + fr) * 32 + fk];
        bf16x8 a1 = *(const bf16x8*)&Ab[(wm + 16 + fr) * 32 + fk];
        bf16x8 b0 = *(const bf16x8*)&Bb[(wn      + fr) * 32 + fk];
        bf16x8 b1 = *(const bf16x8*)&Bb[(wn + 16 + fr) * 32 + fk];
        acc[0][0] = __builtin_amdgcn_mfma_f32_16x16x32_bf16(a0, b0, acc[0][0], 0, 0, 0);
        acc[0][1] = __builtin_amdgcn_mfma_f32_16x16x32_bf16(a0, b1, acc[0][1], 0, 0, 0);
        acc[1][0] = __builtin_amdgcn_mfma_f32_16x16x32_bf16(a1, b0, acc[1][0], 0, 0, 0);
        acc[1][1] = __builtin_amdgcn_mfma_f32_16x16x32_bf16(a1, b1, acc[1][1], 0, 0, 0);
    }
}

// ---------------------------------------------------------------- QKV GEMM, 128x128 tile (m97-style)
// C = Xb[1536,768] * Wb[2304,768]^T. 216 blocks, 4 waves each computing 64x64
// (4x4 of 16x16x32 mfma), BK=32 double-buffered glds staging.
__global__ __launch_bounds__(256) void k_qkv(
        const ushort_t* __restrict__ Xb, const ushort_t* __restrict__ Wb,
        const float* __restrict__ bq, const float* __restrict__ bk,
        const float* __restrict__ bv,
        ushort_t* __restrict__ Qb, ushort_t* __restrict__ Kb,
        ushort_t* __restrict__ Vtb) {
    __shared__ __align__(16) ushort_t As[2][128 * 32];
    __shared__ __align__(16) ushort_t Bs[2][128 * 32];
    const int tid = threadIdx.x, lane = tid & 63, w = tid >> 6;
    const int m0 = blockIdx.y * 128, n0 = blockIdx.x * 128;
    const int frn = lane & 15, fko = (lane >> 4) * 8, frg4 = (lane >> 4) * 4;
    const int wm = (w >> 1) * 64, wn = (w & 1) * 64;
    const int srow = lane >> 2, scol = (lane & 3) * 8;
    f32x4 acc[4][4];
    #pragma unroll
    for (int i = 0; i < 4; i++)
        #pragma unroll
        for (int j = 0; j < 4; j++) acc[i][j] = (f32x4){0.f, 0.f, 0.f, 0.f};
    auto stageAB = [&](int kt, int buf) {
        #pragma unroll
        for (int t = 0; t < 2; ++t) {
            int ins = w * 2 + t;
            int row = ins * 16 + srow;
            glds16(Xb + (size_t)(m0 + row) * D_ + kt + scol, &As[buf][ins * 512]);
            glds16(Wb + (size_t)(n0 + row) * D_ + kt + scol, &Bs[buf][ins * 512]);
        }
    };
    stageAB(0, 0);
    for (int kt = 0; kt < D_; kt += 32) {
        const int cur = (kt >> 5) & 1;
        __syncthreads();
        if (kt + 32 < D_) stageAB(kt + 32, cur ^ 1);
        bf16x8 af[4], bfr[4];
        #pragma unroll
        for (int i = 0; i < 4; ++i) {
            af[i]  = *(const bf16x8*)&As[cur][(wm + i * 16 + frn) * 32 + fko];
            bfr[i] = *(const bf16x8*)&Bs[cur][(wn + i * 16 + frn) * 32 + fko];
        }
        #pragma unroll
        for (int i = 0; i < 4; ++i)
            #pragma unroll
            for (int j = 0; j < 4; ++j)
                acc[i][j] = __builtin_amdgcn_mfma_f32_16x16x32_bf16(af[i], bfr[j], acc[i][j], 0, 0, 0);
    }
    #pragma unroll
    for (int j = 0; j < 4; ++j) {
        int gcol = n0 + wn + j * 16 + frn;
        int gsel = gcol / D_, d768 = gcol - gsel * D_;
        int h = d768 / DH_, d = d768 - h * DH_;
        float bias = (gsel == 0 ? bq : (gsel == 1 ? bk : bv))[d768];
        #pragma unroll
        for (int i = 0; i < 4; ++i) {
            int grow0 = m0 + wm + i * 16 + frg4;
            int b = grow0 / S_, s0 = grow0 - b * S_;
            int bh = b * H_ + h;
            if (gsel == 2) {
                ushort4 o4;
                o4.x = f2bf(acc[i][j][0] + bias);
                o4.y = f2bf(acc[i][j][1] + bias);
                o4.z = f2bf(acc[i][j][2] + bias);
                o4.w = f2bf(acc[i][j][3] + bias);
                *(ushort4*)&Vtb[((size_t)bh * DH_ + d) * S_ + s0] = o4;
            } else if (gsel == 1) {
                #pragma unroll
                for (int r = 0; r < 4; r++)
                    Kb[(((size_t)bh * 12 + (d >> 3)) * S_ + s0 + r) * 8 + (d & 7)] =
                        f2bf(acc[i][j][r] + bias);
            } else {
                #pragma unroll
                for (int r = 0; r < 4; r++)
                    Qb[((size_t)bh * S_ + s0 + r) * DH_ + d] = f2bf(acc[i][j][r] + bias);
            }
        }
    }
}

// ---------------------------------------------------------------- qcoef
__global__ __launch_bounds__(256) void k_qcoef(
        const ushort_t* __restrict__ Qb,
        const float* __restrict__ Wd, const float* __restrict__ bd,
        const float* __restrict__ Wa, const float* __restrict__ ba,
        float* __restrict__ qcoef) {
    const int wave = threadIdx.x >> 6, lane = threadIdx.x & 63;
    const int row = blockIdx.x * 4 + wave;
    const ushort_t* q = Qb + (size_t)row * DH_;
    float e0 = bf2f(q[lane]);
    float c0 = e0 * Wd[lane];
    float c1 = e0 * Wa[lane];
    float c2 = e0 * (bd[lane] + ba[lane]);
    if (lane < 32) {
        int d = 64 + lane;
        float e1 = bf2f(q[d]);
        c0 += e1 * Wd[d];
        c1 += e1 * Wa[d];
        c2 += e1 * (bd[d] + ba[d]);
    }
    #pragma unroll
    for (int o = 32; o > 0; o >>= 1) {
        c0 += __shfl_down(c0, o);
        c1 += __shfl_down(c1, o);
        c2 += __shfl_down(c2, o);
    }
    if (lane == 0) {
        qcoef[row * 3 + 0] = c0;
        qcoef[row * 3 + 1] = c1;
        qcoef[row * 3 + 2] = c2;
    }
}

// ---------------------------------------------------------------- fused flash v5
// XCD-pinned: idx = t*16 + bh -> idx%8 = h, so all 48 blocks of a bh (plus its
// b-sibling) land on ONE XCD: K+V working set 588KB stays L2-resident (was L3).
// dist/ang read as fp16 (half traffic), LDS [16][64] f16 with even-key XOR
// unit-swizzle (u ^= row&14) applied on glds SOURCE and read (T21 involution).
// Swapped QK^T, in-reg softmax/P, LDS-staged swizzled V (unchanged from v4).
#define FL1B 16384   // Ks 12288 ([12 grp][64 row][8]) + Dd 2048 + Da 2048
#define VBUF 24576   // [96 d][16 units][16B], two of these overlay loop1 bufs
__global__ __launch_bounds__(256, 3) void k_flash(
        const ushort_t* __restrict__ Qb, const ushort_t* __restrict__ Kb,
        const ushort_t* __restrict__ Vtb, const float* __restrict__ qcoef,
        const ushort_t* __restrict__ Dh, const ushort_t* __restrict__ Ah,
        const float* __restrict__ mask,
        float* __restrict__ probs, ushort_t* __restrict__ Ctxb) {
    __shared__ __align__(16) char sm[2 * VBUF + 512];
    float* mstat = (float*)(sm + 2 * VBUF);          // [4][16]
    float* lstat = (float*)(sm + 2 * VBUF + 256);    // [4][16]
    const int idx = blockIdx.x;
    const int bh = idx & 15, t = idx >> 4;           // idx%8 == h -> XCD pin
    const int b = bh >> 3, h = bh & 7;
    const int r0 = t * 16;
    const int tid = threadIdx.x, lane = tid & 63, w = tid >> 6;
    const int frn = lane & 15, g = lane >> 4;
    const ushort_t* Qbh = Qb + (size_t)bh * S_ * DH_;
    const ushort_t* Kbh = Kb + (size_t)bh * 12 * S_ * 8;   // [grp][s][8]
    const ushort_t* Vbh = Vtb + (size_t)bh * DH_ * S_;

    auto stage = [&](int c) {
        char* bufc = sm + (c & 1) * FL1B;
        ushort_t* Ks = (ushort_t*)bufc;
        #pragma unroll
        for (int tt = 0; tt < 3; ++tt) {
            int grp = w * 3 + tt;
            glds16(Kbh + (((size_t)grp * S_ + c * 64 + lane) << 3), Ks + grp * 512);
        }
        // dist/ang fp16 [16][64], swizzled: LDS unit u holds global unit u^(row&14)
        int row8 = ((w & 1) << 3) + (lane >> 3);
        int usrc = (2 * (lane & 7)) ^ (row8 & 14);
        const ushort_t* srcm = (w >> 1) ? Ah : Dh;
        glds16(srcm + ((size_t)(b * S_ + r0 + row8)) * S_ + c * 64 + usrc * 4,
               bufc + 12288 + ((w >> 1) << 11) + ((w & 1) << 10));
    };
    // stage V columns [p*128, p*128+128) for all 96 d-rows into Vbuf[p&1];
    // LDS 16B-unit (d,u) holds global cols (u ^ (d&15))*8 .. +7 of the pair.
    auto stage_v = [&](int p) {
        ushort_t* Vs = (ushort_t*)(sm + (p & 1) * VBUF);
        const int c0 = p * 128;
        #pragma unroll
        for (int tt = 0; tt < 6; ++tt) {
            int q = w * 6 + tt;
            int d = 4 * q + (lane >> 4);
            int ug = (lane & 15) ^ (d & 15);
            glds16(Vbh + (size_t)d * S_ + c0 + ug * 8, Vs + q * 512);
        }
    };

    stage(0);

    // Q fragments (B operand of swapped QK^T): row = q-row = frn
    bf16x8 aq0, aq1, aq2;
    {
        const ushort_t* qp = Qbh + (size_t)(r0 + frn) * DH_ + g * 8;
        aq0 = *(const bf16x8*)qp;
        aq1 = *(const bf16x8*)(qp + 32);
        aq2 = *(const bf16x8*)(qp + 64);
    }
    float qc0, qc1, qc2;
    {
        const float* qp = qcoef + ((size_t)bh * S_ + r0 + frn) * 3;
        qc0 = qp[0]; qc1 = qp[1]; qc2 = qp[2];
    }
    const float isq = 0.10206207261596577f;   // 1/sqrt(96)
    const int daswz = (((w * 4 + g) ^ (frn & 14)) << 2);  // fp16-unit swizzled offset
    const int jrow = (16 * w + frn) * 8;                  // K frag row offset (ushorts)

    // ---- loop 1: scores in regs (one-ahead prefetch, 1 barrier/chunk)
    f32x4 acc[12];
    __syncthreads();     // chunk 0 staged
    #pragma unroll
    for (int c = 0; c < 12; ++c) {
        if (c < 11) stage(c + 1);
        char* bufc = sm + (c & 1) * FL1B;
        const ushort_t* Ks = (const ushort_t*)bufc;
        bf16x8 k0 = *(const bf16x8*)&Ks[(g    ) * 512 + jrow];
        bf16x8 k1 = *(const bf16x8*)&Ks[(g + 4) * 512 + jrow];
        bf16x8 k2 = *(const bf16x8*)&Ks[(g + 8) * 512 + jrow];
        f32x4 ca = (f32x4){0.f, 0.f, 0.f, 0.f};
        ca = __builtin_amdgcn_mfma_f32_16x16x32_bf16(k0, aq0, ca, 0, 0, 0);
        ca = __builtin_amdgcn_mfma_f32_16x16x32_bf16(k1, aq1, ca, 0, 0, 0);
        ca = __builtin_amdgcn_mfma_f32_16x16x32_bf16(k2, aq2, ca, 0, 0, 0);
        // acc[c][rr]: q-row = frn, col j = c*64 + w*16 + 4g + rr
        f16x4 d4 = *(const f16x4*)((const ushort_t*)(bufc + 12288) + frn * 64 + daswz);
        f16x4 a4 = *(const f16x4*)((const ushort_t*)(bufc + 14336) + frn * 64 + daswz);
        float4 m4 = *(const float4*)(mask + b * S_ + c * 64 + w * 16 + g * 4);
        f32x4 o;
        o[0] = ca[0] * isq + (float)d4[0] * qc0 + (float)a4[0] * qc1 + qc2 + (1.f - m4.x) * -10000.f;
        o[1] = ca[1] * isq + (float)d4[1] * qc0 + (float)a4[1] * qc1 + qc2 + (1.f - m4.y) * -10000.f;
        o[2] = ca[2] * isq + (float)d4[2] * qc0 + (float)a4[2] * qc1 + qc2 + (1.f - m4.z) * -10000.f;
        o[3] = ca[3] * isq + (float)d4[3] * qc0 + (float)a4[3] * qc1 + qc2 + (1.f - m4.w) * -10000.f;
        acc[c] = o;
        __syncthreads();
    }

    // ---- softmax (exact; q-row = frn is lane-local); V pair 0 prefetched under it
    stage_v(0);
    float mx = -1e30f;
    #pragma unroll
    for (int c = 0; c < 12; ++c)
        #pragma unroll
        for (int r = 0; r < 4; ++r) mx = fmaxf(mx, acc[c][r]);
    mx = fmaxf(mx, __shfl_xor(mx, 16));
    mx = fmaxf(mx, __shfl_xor(mx, 32));
    if (g == 0) mstat[w * 16 + frn] = mx;
    __syncthreads();
    float mf = fmaxf(fmaxf(mstat[frn], mstat[16 + frn]),
                     fmaxf(mstat[32 + frn], mstat[48 + frn]));
    float sum = 0.f;
    #pragma unroll
    for (int c = 0; c < 12; ++c)
        #pragma unroll
        for (int r = 0; r < 4; ++r) {
            float e = __expf(acc[c][r] - mf);
            acc[c][r] = e;
            sum += e;
        }
    sum += __shfl_xor(sum, 16);
    sum += __shfl_xor(sum, 32);
    if (g == 0) lstat[w * 16 + frn] = sum;
    __syncthreads();
    float inv = 1.f / (lstat[frn] + lstat[16 + frn] + lstat[32 + frn] + lstat[48 + frn]);

    // ---- probs write (f32, from regs) + PV (P in-register, V from swizzled LDS)
    f32x4 accO[6];
    #pragma unroll
    for (int i = 0; i < 6; ++i) accO[i] = (f32x4){0.f, 0.f, 0.f, 0.f};
    float* prow = probs + ((size_t)bh * S_ + r0 + frn) * S_ + w * 16 + g * 4;
    const int vsub = (g & 1) << 2;          // 8B-half within 16B unit (elements)
    const int u0 = 2 * w + (g >> 1);
    #pragma unroll
    for (int p = 0; p < 6; ++p) {
        if (p < 5) stage_v(p + 1);
        const ushort_t* Vs = (const ushort_t*)(sm + (p & 1) * VBUF);
        const int c = 2 * p;
        float4 pw;
        pw.x = acc[c][0] * inv; pw.y = acc[c][1] * inv;
        pw.z = acc[c][2] * inv; pw.w = acc[c][3] * inv;
        *(float4*)(prow + c * 64) = pw;
        pw.x = acc[c + 1][0] * inv; pw.y = acc[c + 1][1] * inv;
        pw.z = acc[c + 1][2] * inv; pw.w = acc[c + 1][3] * inv;
        *(float4*)(prow + (c + 1) * 64) = pw;
        // A operand: P[q-row frn][kappa 8g+e]; e<4 -> chunk c, e>=4 -> chunk c+1
        union { bf16x8 v; ushort_t u[8]; } pa;
        #pragma unroll
        for (int r = 0; r < 4; ++r) {
            pa.u[r]     = f2bf(acc[c][r]);
            pa.u[r + 4] = f2bf(acc[c + 1][r]);
        }
        #pragma unroll
        for (int nt = 0; nt < 6; ++nt) {
            int d = nt * 16 + frn;           // d&15 == frn
            const ushort_t* vr = Vs + d * 128 + vsub;
            union { bf16x8 v; uint2 q2[2]; } vb;
            vb.q2[0] = *(const uint2*)(vr + (((u0    ) ^ frn) << 3));
            vb.q2[1] = *(const uint2*)(vr + (((u0 + 8) ^ frn) << 3));
            accO[nt] = __builtin_amdgcn_mfma_f32_16x16x32_bf16(pa.v, vb.v, accO[nt], 0, 0, 0);
        }
        __syncthreads();
    }

    // ---- cross-wave reduce (each wave holds its kappa-slice partial) + ctx
    float* ctxred = (float*)sm;
    {
        int zr = tid >> 4, zc = tid & 15;
        #pragma unroll
        for (int i = 0; i < 6; ++i) ctxred[zr * 100 + i * 16 + zc] = 0.f;
    }
    __syncthreads();
    #pragma unroll
    for (int nt = 0; nt < 6; ++nt)
        #pragma unroll
        for (int r = 0; r < 4; ++r)
            atomicAdd(&ctxred[(4 * g + r) * 100 + nt * 16 + frn], accO[nt][r]);
    __syncthreads();
    {
        int zr = tid >> 4, zc = tid & 15;
        float ivr = 1.f / (lstat[zr] + lstat[16 + zr] + lstat[32 + zr] + lstat[48 + zr]);
        ushort_t* crow = Ctxb + ((size_t)b * S_ + r0 + zr) * D_ + h * DH_;
        #pragma unroll
        for (int i = 0; i < 6; ++i)
            crow[i * 16 + zc] = f2bf(ctxred[zr * 100 + i * 16 + zc] * ivr);
    }
}

// ---------------------------------------------------------------- out GEMM + bias + residual
__global__ __launch_bounds__(256) void k_out(
        const ushort_t* __restrict__ Ctxb, const ushort_t* __restrict__ Wob,
        const float* __restrict__ bo, const float* __restrict__ hidden,
        float* __restrict__ xbuf) {
    __shared__ __align__(16) ushort_t As[2 * 64 * 32];
    __shared__ __align__(16) ushort_t Bs[2 * 64 * 32];
    f32x4 acc[2][2];
    #pragma unroll
    for (int i = 0; i < 2; i++)
        #pragma unroll
        for (int j = 0; j < 2; j++) acc[i][j] = (f32x4){0.f, 0.f, 0.f, 0.f};
    const int m0 = blockIdx.y * 64, n0 = blockIdx.x * 64;
    gemm64_dbuf(Ctxb, D_, Wob, D_, D_, m0, n0, As, Bs, acc);
    const int lane = threadIdx.x & 63, wave = threadIdx.x >> 6;
    const int wm = (wave >> 1) * 32, wn = (wave & 1) * 32;
    #pragma unroll
    for (int ni = 0; ni < 2; ni++) {
        int gcol = n0 + wn + ni * 16 + (lane & 15);
        float bias = bo[gcol];
        #pragma unroll
        for (int mi = 0; mi < 2; mi++) {
            #pragma unroll
            for (int r = 0; r < 4; r++) {
                int grow = m0 + wm + mi * 16 + (lane >> 4) * 4 + r;
                xbuf[(size_t)grow * D_ + gcol] =
                    acc[mi][ni][r] + bias + hidden[(size_t)grow * D_ + gcol];
            }
        }
    }
}

// ---------------------------------------------------------------- LayerNorm
__global__ __launch_bounds__(256) void k_ln(
        const float* __restrict__ xbuf, const float* __restrict__ g,
        const float* __restrict__ bb, float* __restrict__ out) {
    const float* x = xbuf + (size_t)blockIdx.x * D_;
    const int t = threadIdx.x;
    float a0 = x[t], a1 = x[t + 256], a2 = x[t + 512];
    float s = a0 + a1 + a2;
    float ss = a0 * a0 + a1 * a1 + a2 * a2;
    __shared__ float r1[4], r2[4];
    #pragma unroll
    for (int o = 32; o > 0; o >>= 1) { s += __shfl_down(s, o); ss += __shfl_down(ss, o); }
    if ((t & 63) == 0) { r1[t >> 6] = s; r2[t >> 6] = ss; }
    __syncthreads();
    float ts = r1[0] + r1[1] + r1[2] + r1[3];
    float tss = r2[0] + r2[1] + r2[2] + r2[3];
    float mu = ts * (1.0f / D_);
    float var = tss * (1.0f / D_) - mu * mu;
    float rstd = rsqrtf(var + 1e-5f);
    float* o = out + (size_t)blockIdx.x * D_;
    o[t]       = (a0 - mu) * rstd * g[t]       + bb[t];
    o[t + 256] = (a1 - mu) * rstd * g[t + 256] + bb[t + 256];
    o[t + 512] = (a2 - mu) * rstd * g[t + 512] + bb[t + 512];
}

// ---------------------------------------------------------------- launch
extern "C" void kernel_launch(void* const* d_in, const int* in_sizes, int n_in,
                              void* d_out, int out_size, void* d_ws, size_t ws_size,
                              hipStream_t stream) {
    const float* X     = (const float*)d_in[0];
    const float* distm = (const float*)d_in[1];
    const float* angm  = (const float*)d_in[2];
    const float* mask  = (const float*)d_in[3];
    const float* Wq    = (const float*)d_in[4];
    const float* bq    = (const float*)d_in[5];
    const float* Wk    = (const float*)d_in[6];
    const float* bk    = (const float*)d_in[7];
    const float* Wv    = (const float*)d_in[8];
    const float* bv    = (const float*)d_in[9];
    const float* Wd    = (const float*)d_in[10];
    const float* bd    = (const float*)d_in[11];
    const float* Wa    = (const float*)d_in[12];
    const float* ba    = (const float*)d_in[13];
    const float* Wo    = (const float*)d_in[14];
    const float* bo    = (const float*)d_in[15];
    const float* ln_g  = (const float*)d_in[16];
    const float* ln_b  = (const float*)d_in[17];

    float* outp  = (float*)d_out;                        // [B,S,D]
    float* probs = (float*)d_out + (size_t)B_ * S_ * D_; // [B,H,S,S]

    char* ws = (char*)d_ws;
    ushort_t* Xb    = (ushort_t*)(ws + 0);          // 2,359,296 B
    ushort_t* Wb    = (ushort_t*)(ws + 2359296);    // 4,718,592 B
    ushort_t* Qb    = (ushort_t*)(ws + 7077888);    // 2,359,296 B
    ushort_t* Kb    = (ushort_t*)(ws + 9437184);    // 2,359,296 B  [bh][grp][s][8]
    ushort_t* Vtb   = (ushort_t*)(ws + 11796480);   // 2,359,296 B
    ushort_t* Ctxb  = (ushort_t*)(ws + 14155776);   // 2,359,296 B
    float*    qcoef = (float*)   (ws + 16515072);   //   147,456 B
    float*    xbuf  = (float*)   (ws + 16662528);   // 4,718,592 B (end ~21.4 MB)
    // Dh/Ah (fp16 dist/ang) alias xbuf: written by k_convert, read by k_flash,
    // dead once k_out overwrites xbuf (stream-ordered).
    ushort_t* Dh    = (ushort_t*)(ws + 16662528);   // 2,359,296 B
    ushort_t* Ah    = (ushort_t*)(ws + 16662528 + 2359296);

    k_convert<<<5760, 256, 0, stream>>>(X, Wq, Wk, Wv, Wo, distm, angm, Xb, Wb, Dh, Ah);
    k_qkv<<<dim3(18, 12), 256, 0, stream>>>(Xb, Wb, bq, bk, bv, Qb, Kb, Vtb);
    k_qcoef<<<3072, 256, 0, stream>>>(Qb, Wd, bd, Wa, ba, qcoef);
    k_flash<<<768, 256, 0, stream>>>(Qb, Kb, Vtb, qcoef, Dh, Ah, mask, probs, Ctxb);
    k_out<<<dim3(12, 24), 256, 0, stream>>>(Ctxb, Wb + (size_t)2304 * 768, bo, X, xbuf);
    k_ln<<<1536, 256, 0, stream>>>(xbuf, ln_g, ln_b, outp);
}

// Round 5
// 186.219 us; speedup vs baseline: 1.0293x; 1.0293x over previous
//
#include <hip/hip_runtime.h>
#include <stdint.h>

#define B_  2
#define S_  768
#define D_  768
#define H_  8
#define DH_ 96

typedef unsigned short ushort_t;
typedef __bf16 bf16x8 __attribute__((ext_vector_type(8)));
typedef float  f32x4  __attribute__((ext_vector_type(4)));
typedef _Float16 f16x4 __attribute__((ext_vector_type(4)));

__device__ inline ushort_t f2bf(float f) {
    union { float f; unsigned int u; } v; v.f = f;
    unsigned int u = v.u;
    unsigned int r = u + 0x7fffu + ((u >> 16) & 1u);
    return (ushort_t)(r >> 16);
}
__device__ inline float bf2f(ushort_t u) {
    union { unsigned int i; float f; } c; c.i = ((unsigned int)u) << 16;
    return c.f;
}
__device__ inline ushort_t f2h(float f) {
    union { _Float16 h; ushort_t u; } c; c.h = (_Float16)f; return c.u;
}

// async global->LDS, 16B per lane; LDS dest is wave-uniform base + lane*16.
__device__ inline void glds16(const void* gp, void* lp) {
    auto g = reinterpret_cast<const __attribute__((address_space(1))) uint32_t*>(
        reinterpret_cast<uintptr_t>(gp));
    auto l = reinterpret_cast<__attribute__((address_space(3))) uint32_t*>(
        reinterpret_cast<uintptr_t>(lp));
    __builtin_amdgcn_global_load_lds(g, l, 16, 0, 0);
}

// counted-wait helpers (T4): raw barrier, no vmcnt(0) drain. rule #18 fences.
#define SBAR()  { __builtin_amdgcn_sched_barrier(0); __builtin_amdgcn_s_barrier(); \
                  __builtin_amdgcn_sched_barrier(0); }
#define WAIT_VM(N) { asm volatile("s_waitcnt vmcnt(" #N ")" ::: "memory"); \
                     __builtin_amdgcn_sched_barrier(0); }
#define WAIT_LGKM0() { asm volatile("s_waitcnt lgkmcnt(0)" ::: "memory"); \
                       __builtin_amdgcn_sched_barrier(0); }

// ---------------------------------------------------------------- convert
// X,Wq..Wo -> bf16; dist/ang -> fp16 (into xbuf region, dead until k_out).
__global__ __launch_bounds__(256) void k_convert(
        const float* __restrict__ X, const float* __restrict__ Wq,
        const float* __restrict__ Wk, const float* __restrict__ Wv,
        const float* __restrict__ Wo, const float* __restrict__ distm,
        const float* __restrict__ angm,
        ushort_t* __restrict__ Xb, ushort_t* __restrict__ Wb,
        ushort_t* __restrict__ Dh, ushort_t* __restrict__ Ah) {
    const int NX4 = (B_ * S_ * D_) / 4;   // 294912
    const int NW4 = (D_ * D_) / 4;        // 147456
    const int NWall = 4 * NW4;            // 589824
    const int ND4 = (B_ * S_ * S_) / 4;   // 294912
    int i = blockIdx.x * blockDim.x + threadIdx.x;
    float4 v;
    ushort_t* dst;
    bool h16 = false;
    if (i < NX4) {
        v = ((const float4*)X)[i];
        dst = Xb + i * 4;
    } else if (i < NX4 + NWall) {
        int wi = i - NX4;
        int sel = wi / NW4;
        int off = wi - sel * NW4;
        const float* src = (sel == 0) ? Wq : (sel == 1) ? Wk : (sel == 2) ? Wv : Wo;
        v = ((const float4*)src)[off];
        dst = Wb + wi * 4;
    } else if (i < NX4 + NWall + ND4) {
        int off = i - NX4 - NWall;
        v = ((const float4*)distm)[off];
        dst = Dh + off * 4; h16 = true;
    } else {
        int off = i - NX4 - NWall - ND4;
        v = ((const float4*)angm)[off];
        dst = Ah + off * 4; h16 = true;
    }
    ushort4 o;
    if (h16) { o.x = f2h(v.x); o.y = f2h(v.y); o.z = f2h(v.z); o.w = f2h(v.w); }
    else     { o.x = f2bf(v.x); o.y = f2bf(v.y); o.z = f2bf(v.z); o.w = f2bf(v.w); }
    *(ushort4*)dst = o;
}

// ---------------------------------------------------------------- 64x64 GEMM, dbuf + counted vmcnt
// Per wave 2 glds per K-step; vmcnt(2) keeps next-tile staging in flight
// across the barrier (T4) instead of the compiler's vmcnt(0) drain.
__device__ inline void gemm64_dbuf(
        const ushort_t* __restrict__ A, int lda,
        const ushort_t* __restrict__ Bt, int ldb,
        int K, int m0, int n0,
        ushort_t* As, ushort_t* Bs, f32x4 acc[2][2]) {
    const int tid  = threadIdx.x;
    const int lane = tid & 63, wave = tid >> 6;
    const int wm = (wave >> 1) * 32, wn = (wave & 1) * 32;
    const int fr = lane & 15, fk = (lane >> 4) * 8;
    const ushort_t* Ap = A  + (size_t)(m0 + wave * 16 + (lane >> 2)) * lda + (lane & 3) * 8;
    const ushort_t* Bp = Bt + (size_t)(n0 + wave * 16 + (lane >> 2)) * ldb + (lane & 3) * 8;
    glds16(Ap, As + wave * 512);
    glds16(Bp, Bs + wave * 512);
    for (int kt = 0; kt < K; kt += 32) {
        const int cur = (kt >> 5) & 1;
        if (kt + 32 < K) {
            glds16(Ap + kt + 32, As + (cur ^ 1) * 2048 + wave * 512);
            glds16(Bp + kt + 32, Bs + (cur ^ 1) * 2048 + wave * 512);
            WAIT_VM(2)                 // stage(kt) done; stage(kt+32) stays in flight
        } else {
            WAIT_VM(0)
        }
        SBAR()
        const ushort_t* Ab = As + cur * 2048;
        const ushort_t* Bb = Bs + cur * 2048;
        bf16x8 a0 = *(const bf16x8*)&Ab[(wm      + fr) * 32 + fk];
        bf16x8 a1 = *(const bf16x8*)&Ab[(wm + 16 + fr) * 32 + fk];
        bf16x8 b0 = *(const bf16x8*)&Bb[(wn      + fr) * 32 + fk];
        bf16x8 b1 = *(const bf16x8*)&Bb[(wn + 16 + fr) * 32 + fk];
        acc[0][0] = __builtin_amdgcn_mfma_f32_16x16x32_bf16(a0, b0, acc[0][0], 0, 0, 0);
        acc[0][1] = __builtin_amdgcn_mfma_f32_16x16x32_bf16(a0, b1, acc[0][1], 0, 0, 0);
        acc[1][0] = __builtin_amdgcn_mfma_f32_16x16x32_bf16(a1, b0, acc[1][0], 0, 0, 0);
        acc[1][1] = __builtin_amdgcn_mfma_f32_16x16x32_bf16(a1, b1, acc[1][1], 0, 0, 0);
        WAIT_LGKM0()                   // my reads of buf cur done
        SBAR()                         // safe to overwrite buf cur next iter
    }
}

// ---------------------------------------------------------------- QKV GEMM, 128x128 tile + counted vmcnt
__global__ __launch_bounds__(256) void k_qkv(
        const ushort_t* __restrict__ Xb, const ushort_t* __restrict__ Wb,
        const float* __restrict__ bq, const float* __restrict__ bk,
        const float* __restrict__ bv,
        ushort_t* __restrict__ Qb, ushort_t* __restrict__ Kb,
        ushort_t* __restrict__ Vtb) {
    __shared__ __align__(16) ushort_t As[2][128 * 32];
    __shared__ __align__(16) ushort_t Bs[2][128 * 32];
    const int tid = threadIdx.x, lane = tid & 63, w = tid >> 6;
    const int m0 = blockIdx.y * 128, n0 = blockIdx.x * 128;
    const int frn = lane & 15, fko = (lane >> 4) * 8, frg4 = (lane >> 4) * 4;
    const int wm = (w >> 1) * 64, wn = (w & 1) * 64;
    const int srow = lane >> 2, scol = (lane & 3) * 8;
    f32x4 acc[4][4];
    #pragma unroll
    for (int i = 0; i < 4; i++)
        #pragma unroll
        for (int j = 0; j < 4; j++) acc[i][j] = (f32x4){0.f, 0.f, 0.f, 0.f};
    auto stageAB = [&](int kt, int buf) {
        #pragma unroll
        for (int t = 0; t < 2; ++t) {
            int ins = w * 2 + t;
            int row = ins * 16 + srow;
            glds16(Xb + (size_t)(m0 + row) * D_ + kt + scol, &As[buf][ins * 512]);
            glds16(Wb + (size_t)(n0 + row) * D_ + kt + scol, &Bs[buf][ins * 512]);
        }
    };
    stageAB(0, 0);
    for (int kt = 0; kt < D_; kt += 32) {
        const int cur = (kt >> 5) & 1;
        if (kt + 32 < D_) {
            stageAB(kt + 32, cur ^ 1);
            WAIT_VM(4)
        } else {
            WAIT_VM(0)
        }
        SBAR()
        bf16x8 af[4], bfr[4];
        #pragma unroll
        for (int i = 0; i < 4; ++i) {
            af[i]  = *(const bf16x8*)&As[cur][(wm + i * 16 + frn) * 32 + fko];
            bfr[i] = *(const bf16x8*)&Bs[cur][(wn + i * 16 + frn) * 32 + fko];
        }
        #pragma unroll
        for (int i = 0; i < 4; ++i)
            #pragma unroll
            for (int j = 0; j < 4; ++j)
                acc[i][j] = __builtin_amdgcn_mfma_f32_16x16x32_bf16(af[i], bfr[j], acc[i][j], 0, 0, 0);
        WAIT_LGKM0()
        SBAR()
    }
    #pragma unroll
    for (int j = 0; j < 4; ++j) {
        int gcol = n0 + wn + j * 16 + frn;
        int gsel = gcol / D_, d768 = gcol - gsel * D_;
        int h = d768 / DH_, d = d768 - h * DH_;
        float bias = (gsel == 0 ? bq : (gsel == 1 ? bk : bv))[d768];
        #pragma unroll
        for (int i = 0; i < 4; ++i) {
            int grow0 = m0 + wm + i * 16 + frg4;
            int b = grow0 / S_, s0 = grow0 - b * S_;
            int bh = b * H_ + h;
            if (gsel == 2) {
                ushort4 o4;
                o4.x = f2bf(acc[i][j][0] + bias);
                o4.y = f2bf(acc[i][j][1] + bias);
                o4.z = f2bf(acc[i][j][2] + bias);
                o4.w = f2bf(acc[i][j][3] + bias);
                *(ushort4*)&Vtb[((size_t)bh * DH_ + d) * S_ + s0] = o4;
            } else if (gsel == 1) {
                #pragma unroll
                for (int r = 0; r < 4; r++)
                    Kb[(((size_t)bh * 12 + (d >> 3)) * S_ + s0 + r) * 8 + (d & 7)] =
                        f2bf(acc[i][j][r] + bias);
            } else {
                #pragma unroll
                for (int r = 0; r < 4; r++)
                    Qb[((size_t)bh * S_ + s0 + r) * DH_ + d] = f2bf(acc[i][j][r] + bias);
            }
        }
    }
}

// ---------------------------------------------------------------- fused flash v6
// v5 + (a) counted-vmcnt two-barrier schedule in both loops (no vmcnt(0) drain:
// prefetch stays in flight across barriers), (b) qcoef computed in-kernel from
// the Q fragments (k_qcoef launch removed).
#define FL1B 16384   // Ks 12288 ([12 grp][64 row][8]) + Dd 2048 + Da 2048
#define VBUF 24576   // [96 d][16 units][16B]
__global__ __launch_bounds__(256, 3) void k_flash(
        const ushort_t* __restrict__ Qb, const ushort_t* __restrict__ Kb,
        const ushort_t* __restrict__ Vtb,
        const float* __restrict__ Wd, const float* __restrict__ bd,
        const float* __restrict__ Wa, const float* __restrict__ ba,
        const ushort_t* __restrict__ Dh, const ushort_t* __restrict__ Ah,
        const float* __restrict__ mask,
        float* __restrict__ probs, ushort_t* __restrict__ Ctxb) {
    __shared__ __align__(16) char sm[2 * VBUF + 512];
    float* mstat = (float*)(sm + 2 * VBUF);          // [4][16]
    float* lstat = (float*)(sm + 2 * VBUF + 256);    // [4][16]
    const int idx = blockIdx.x;
    const int bh = idx & 15, t = idx >> 4;           // idx%8 == h -> XCD pin
    const int b = bh >> 3, h = bh & 7;
    const int r0 = t * 16;
    const int tid = threadIdx.x, lane = tid & 63, w = tid >> 6;
    const int frn = lane & 15, g = lane >> 4;
    const ushort_t* Qbh = Qb + (size_t)bh * S_ * DH_;
    const ushort_t* Kbh = Kb + (size_t)bh * 12 * S_ * 8;   // [grp][s][8]
    const ushort_t* Vbh = Vtb + (size_t)bh * DH_ * S_;

    // stage chunk c: K contiguous 1KB glds; dist/ang fp16 [16][64] with
    // even-key XOR unit-swizzle (u ^= row&14) on source AND read (T21).
    auto stage = [&](int c) {
        char* bufc = sm + (c & 1) * FL1B;
        ushort_t* Ks = (ushort_t*)bufc;
        #pragma unroll
        for (int tt = 0; tt < 3; ++tt) {
            int grp = w * 3 + tt;
            glds16(Kbh + (((size_t)grp * S_ + c * 64 + lane) << 3), Ks + grp * 512);
        }
        int row8 = ((w & 1) << 3) + (lane >> 3);
        int usrc = (2 * (lane & 7)) ^ (row8 & 14);
        const ushort_t* srcm = (w >> 1) ? Ah : Dh;
        glds16(srcm + ((size_t)(b * S_ + r0 + row8)) * S_ + c * 64 + usrc * 4,
               bufc + 12288 + ((w >> 1) << 11) + ((w & 1) << 10));
    };  // 4 glds per wave
    auto stage_v = [&](int p) {
        ushort_t* Vs = (ushort_t*)(sm + (p & 1) * VBUF);
        const int c0 = p * 128;
        #pragma unroll
        for (int tt = 0; tt < 6; ++tt) {
            int q = w * 6 + tt;
            int d = 4 * q + (lane >> 4);
            int ug = (lane & 15) ^ (d & 15);
            glds16(Vbh + (size_t)d * S_ + c0 + ug * 8, Vs + q * 512);
        }
    };  // 6 glds per wave

    stage(0);

    // Q fragments (B operand of swapped QK^T): row = q-row = frn
    bf16x8 aq0, aq1, aq2;
    {
        const ushort_t* qp = Qbh + (size_t)(r0 + frn) * DH_ + g * 8;
        aq0 = *(const bf16x8*)qp;
        aq1 = *(const bf16x8*)(qp + 32);
        aq2 = *(const bf16x8*)(qp + 64);
    }
    // qcoef fused: lane holds q[frn][f*32+8g..+7]; reduce over g (xor 16,32)
    float qc0 = 0.f, qc1 = 0.f, qc2 = 0.f;
    #pragma unroll
    for (int f = 0; f < 3; ++f) {
        bf16x8 aq = (f == 0) ? aq0 : (f == 1) ? aq1 : aq2;
        #pragma unroll
        for (int e = 0; e < 8; ++e) {
            int d = f * 32 + g * 8 + e;
            float qv = (float)aq[e];
            qc0 += qv * Wd[d];
            qc1 += qv * Wa[d];
            qc2 += qv * (bd[d] + ba[d]);
        }
    }
    qc0 += __shfl_xor(qc0, 16); qc0 += __shfl_xor(qc0, 32);
    qc1 += __shfl_xor(qc1, 16); qc1 += __shfl_xor(qc1, 32);
    qc2 += __shfl_xor(qc2, 16); qc2 += __shfl_xor(qc2, 32);

    const float isq = 0.10206207261596577f;   // 1/sqrt(96)
    const int daswz = (((w * 4 + g) ^ (frn & 14)) << 2);
    const int jrow = (16 * w + frn) * 8;

    // ---- loop 1 (counted): stage(c+1) in flight across both barriers
    f32x4 acc[12];
    #pragma unroll
    for (int c = 0; c < 12; ++c) {
        if (c < 11) {
            stage(c + 1);
            WAIT_VM(4)                 // stage(c) complete; stage(c+1) in flight
        } else {
            WAIT_VM(0)
        }
        SBAR()
        char* bufc = sm + (c & 1) * FL1B;
        const ushort_t* Ks = (const ushort_t*)bufc;
        bf16x8 k0 = *(const bf16x8*)&Ks[(g    ) * 512 + jrow];
        bf16x8 k1 = *(const bf16x8*)&Ks[(g + 4) * 512 + jrow];
        bf16x8 k2 = *(const bf16x8*)&Ks[(g + 8) * 512 + jrow];
        f32x4 ca = (f32x4){0.f, 0.f, 0.f, 0.f};
        ca = __builtin_amdgcn_mfma_f32_16x16x32_bf16(k0, aq0, ca, 0, 0, 0);
        ca = __builtin_amdgcn_mfma_f32_16x16x32_bf16(k1, aq1, ca, 0, 0, 0);
        ca = __builtin_amdgcn_mfma_f32_16x16x32_bf16(k2, aq2, ca, 0, 0, 0);
        f16x4 d4 = *(const f16x4*)((const ushort_t*)(bufc + 12288) + frn * 64 + daswz);
        f16x4 a4 = *(const f16x4*)((const ushort_t*)(bufc + 14336) + frn * 64 + daswz);
        float4 m4 = *(const float4*)(mask + b * S_ + c * 64 + w * 16 + g * 4);
        f32x4 o;
        o[0] = ca[0] * isq + (float)d4[0] * qc0 + (float)a4[0] * qc1 + qc2 + (1.f - m4.x) * -10000.f;
        o[1] = ca[1] * isq + (float)d4[1] * qc0 + (float)a4[1] * qc1 + qc2 + (1.f - m4.y) * -10000.f;
        o[2] = ca[2] * isq + (float)d4[2] * qc0 + (float)a4[2] * qc1 + qc2 + (1.f - m4.z) * -10000.f;
        o[3] = ca[3] * isq + (float)d4[3] * qc0 + (float)a4[3] * qc1 + qc2 + (1.f - m4.w) * -10000.f;
        acc[c] = o;
        WAIT_LGKM0()
        SBAR()                          // reads of buf done; next overwrite safe
    }

    // ---- softmax (raw barriers; stage_v(0) stays in flight underneath)
    stage_v(0);
    float mx = -1e30f;
    #pragma unroll
    for (int c = 0; c < 12; ++c)
        #pragma unroll
        for (int r = 0; r < 4; ++r) mx = fmaxf(mx, acc[c][r]);
    mx = fmaxf(mx, __shfl_xor(mx, 16));
    mx = fmaxf(mx, __shfl_xor(mx, 32));
    if (g == 0) mstat[w * 16 + frn] = mx;
    WAIT_LGKM0()
    SBAR()
    float mf = fmaxf(fmaxf(mstat[frn], mstat[16 + frn]),
                     fmaxf(mstat[32 + frn], mstat[48 + frn]));
    float sum = 0.f;
    #pragma unroll
    for (int c = 0; c < 12; ++c)
        #pragma unroll
        for (int r = 0; r < 4; ++r) {
            float e = __expf(acc[c][r] - mf);
            acc[c][r] = e;
            sum += e;
        }
    sum += __shfl_xor(sum, 16);
    sum += __shfl_xor(sum, 32);
    if (g == 0) lstat[w * 16 + frn] = sum;
    WAIT_LGKM0()
    SBAR()
    float inv = 1.f / (lstat[frn] + lstat[16 + frn] + lstat[32 + frn] + lstat[48 + frn]);

    // ---- loop 2 (counted): probs from regs + PV; V from swizzled LDS
    f32x4 accO[6];
    #pragma unroll
    for (int i = 0; i < 6; ++i) accO[i] = (f32x4){0.f, 0.f, 0.f, 0.f};
    float* prow = probs + ((size_t)bh * S_ + r0 + frn) * S_ + w * 16 + g * 4;
    const int vsub = (g & 1) << 2;
    const int u0 = 2 * w + (g >> 1);
    #pragma unroll
    for (int p = 0; p < 6; ++p) {
        if (p < 5) { stage_v(p + 1); __builtin_amdgcn_sched_barrier(0); }
        // FIFO: ensure stage_v(p) done. outstanding = stage_v(p+1)[6] + probs(p-1)[2]
        if (p == 0)     { WAIT_VM(6) }
        else if (p < 5) { WAIT_VM(8) }
        else            { WAIT_VM(2) }
        SBAR()
        const ushort_t* Vs = (const ushort_t*)(sm + (p & 1) * VBUF);
        const int c = 2 * p;
        float4 pw;
        pw.x = acc[c][0] * inv; pw.y = acc[c][1] * inv;
        pw.z = acc[c][2] * inv; pw.w = acc[c][3] * inv;
        *(float4*)(prow + c * 64) = pw;
        pw.x = acc[c + 1][0] * inv; pw.y = acc[c + 1][1] * inv;
        pw.z = acc[c + 1][2] * inv; pw.w = acc[c + 1][3] * inv;
        *(float4*)(prow + (c + 1) * 64) = pw;
        union { bf16x8 v; ushort_t u[8]; } pa;
        #pragma unroll
        for (int r = 0; r < 4; ++r) {
            pa.u[r]     = f2bf(acc[c][r]);
            pa.u[r + 4] = f2bf(acc[c + 1][r]);
        }
        #pragma unroll
        for (int nt = 0; nt < 6; ++nt) {
            int d = nt * 16 + frn;
            const ushort_t* vr = Vs + d * 128 + vsub;
            union { bf16x8 v; uint2 q2[2]; } vb;
            vb.q2[0] = *(const uint2*)(vr + (((u0    ) ^ frn) << 3));
            vb.q2[1] = *(const uint2*)(vr + (((u0 + 8) ^ frn) << 3));
            accO[nt] = __builtin_amdgcn_mfma_f32_16x16x32_bf16(pa.v, vb.v, accO[nt], 0, 0, 0);
        }
        WAIT_LGKM0()
        SBAR()
    }

    // ---- cross-wave reduce + ctx (ctxred overlays Vbuf0; loop2 fully fenced)
    float* ctxred = (float*)sm;
    {
        int zr = tid >> 4, zc = tid & 15;
        #pragma unroll
        for (int i = 0; i < 6; ++i) ctxred[zr * 100 + i * 16 + zc] = 0.f;
    }
    __syncthreads();
    #pragma unroll
    for (int nt = 0; nt < 6; ++nt)
        #pragma unroll
        for (int r = 0; r < 4; ++r)
            atomicAdd(&ctxred[(4 * g + r) * 100 + nt * 16 + frn], accO[nt][r]);
    __syncthreads();
    {
        int zr = tid >> 4, zc = tid & 15;
        float ivr = 1.f / (lstat[zr] + lstat[16 + zr] + lstat[32 + zr] + lstat[48 + zr]);
        ushort_t* crow = Ctxb + ((size_t)b * S_ + r0 + zr) * D_ + h * DH_;
        #pragma unroll
        for (int i = 0; i < 6; ++i)
            crow[i * 16 + zc] = f2bf(ctxred[zr * 100 + i * 16 + zc] * ivr);
    }
}

// ---------------------------------------------------------------- out GEMM + bias + residual
__global__ __launch_bounds__(256) void k_out(
        const ushort_t* __restrict__ Ctxb, const ushort_t* __restrict__ Wob,
        const float* __restrict__ bo, const float* __restrict__ hidden,
        float* __restrict__ xbuf) {
    __shared__ __align__(16) ushort_t As[2 * 64 * 32];
    __shared__ __align__(16) ushort_t Bs[2 * 64 * 32];
    f32x4 acc[2][2];
    #pragma unroll
    for (int i = 0; i < 2; i++)
        #pragma unroll
        for (int j = 0; j < 2; j++) acc[i][j] = (f32x4){0.f, 0.f, 0.f, 0.f};
    const int m0 = blockIdx.y * 64, n0 = blockIdx.x * 64;
    gemm64_dbuf(Ctxb, D_, Wob, D_, D_, m0, n0, As, Bs, acc);
    const int lane = threadIdx.x & 63, wave = threadIdx.x >> 6;
    const int wm = (wave >> 1) * 32, wn = (wave & 1) * 32;
    #pragma unroll
    for (int ni = 0; ni < 2; ni++) {
        int gcol = n0 + wn + ni * 16 + (lane & 15);
        float bias = bo[gcol];
        #pragma unroll
        for (int mi = 0; mi < 2; mi++) {
            #pragma unroll
            for (int r = 0; r < 4; r++) {
                int grow = m0 + wm + mi * 16 + (lane >> 4) * 4 + r;
                xbuf[(size_t)grow * D_ + gcol] =
                    acc[mi][ni][r] + bias + hidden[(size_t)grow * D_ + gcol];
            }
        }
    }
}

// ---------------------------------------------------------------- LayerNorm
__global__ __launch_bounds__(256) void k_ln(
        const float* __restrict__ xbuf, const float* __restrict__ g,
        const float* __restrict__ bb, float* __restrict__ out) {
    const float* x = xbuf + (size_t)blockIdx.x * D_;
    const int t = threadIdx.x;
    float a0 = x[t], a1 = x[t + 256], a2 = x[t + 512];
    float s = a0 + a1 + a2;
    float ss = a0 * a0 + a1 * a1 + a2 * a2;
    __shared__ float r1[4], r2[4];
    #pragma unroll
    for (int o = 32; o > 0; o >>= 1) { s += __shfl_down(s, o); ss += __shfl_down(ss, o); }
    if ((t & 63) == 0) { r1[t >> 6] = s; r2[t >> 6] = ss; }
    __syncthreads();
    float ts = r1[0] + r1[1] + r1[2] + r1[3];
    float tss = r2[0] + r2[1] + r2[2] + r2[3];
    float mu = ts * (1.0f / D_);
    float var = tss * (1.0f / D_) - mu * mu;
    float rstd = rsqrtf(var + 1e-5f);
    float* o = out + (size_t)blockIdx.x * D_;
    o[t]       = (a0 - mu) * rstd * g[t]       + bb[t];
    o[t + 256] = (a1 - mu) * rstd * g[t + 256] + bb[t + 256];
    o[t + 512] = (a2 - mu) * rstd * g[t + 512] + bb[t + 512];
}

// ---------------------------------------------------------------- launch
extern "C" void kernel_launch(void* const* d_in, const int* in_sizes, int n_in,
                              void* d_out, int out_size, void* d_ws, size_t ws_size,
                              hipStream_t stream) {
    const float* X     = (const float*)d_in[0];
    const float* distm = (const float*)d_in[1];
    const float* angm  = (const float*)d_in[2];
    const float* mask  = (const float*)d_in[3];
    const float* Wq    = (const float*)d_in[4];
    const float* bq    = (const float*)d_in[5];
    const float* Wk    = (const float*)d_in[6];
    const float* bk    = (const float*)d_in[7];
    const float* Wv    = (const float*)d_in[8];
    const float* bv    = (const float*)d_in[9];
    const float* Wd    = (const float*)d_in[10];
    const float* bd    = (const float*)d_in[11];
    const float* Wa    = (const float*)d_in[12];
    const float* ba    = (const float*)d_in[13];
    const float* Wo    = (const float*)d_in[14];
    const float* bo    = (const float*)d_in[15];
    const float* ln_g  = (const float*)d_in[16];
    const float* ln_b  = (const float*)d_in[17];

    float* outp  = (float*)d_out;                        // [B,S,D]
    float* probs = (float*)d_out + (size_t)B_ * S_ * D_; // [B,H,S,S]

    char* ws = (char*)d_ws;
    ushort_t* Xb    = (ushort_t*)(ws + 0);          // 2,359,296 B
    ushort_t* Wb    = (ushort_t*)(ws + 2359296);    // 4,718,592 B
    ushort_t* Qb    = (ushort_t*)(ws + 7077888);    // 2,359,296 B
    ushort_t* Kb    = (ushort_t*)(ws + 9437184);    // 2,359,296 B  [bh][grp][s][8]
    ushort_t* Vtb   = (ushort_t*)(ws + 11796480);   // 2,359,296 B
    ushort_t* Ctxb  = (ushort_t*)(ws + 14155776);   // 2,359,296 B
    float*    xbuf  = (float*)   (ws + 16662528);   // 4,718,592 B (end ~21.4 MB)
    // Dh/Ah (fp16 dist/ang) alias xbuf: written by k_convert, read by k_flash,
    // dead once k_out overwrites xbuf (stream-ordered).
    ushort_t* Dh    = (ushort_t*)(ws + 16662528);   // 2,359,296 B
    ushort_t* Ah    = (ushort_t*)(ws + 16662528 + 2359296);

    k_convert<<<5760, 256, 0, stream>>>(X, Wq, Wk, Wv, Wo, distm, angm, Xb, Wb, Dh, Ah);
    k_qkv<<<dim3(18, 12), 256, 0, stream>>>(Xb, Wb, bq, bk, bv, Qb, Kb, Vtb);
    k_flash<<<768, 256, 0, stream>>>(Qb, Kb, Vtb, Wd, bd, Wa, ba, Dh, Ah, mask, probs, Ctxb);
    k_out<<<dim3(12, 24), 256, 0, stream>>>(Ctxb, Wb + (size_t)2304 * 768, bo, X, xbuf);
    k_ln<<<1536, 256, 0, stream>>>(xbuf, ln_g, ln_b, outp);
}